// Round 17
// baseline (146.154 us; speedup 1.0000x reference)
//
#include <hip/hip_runtime.h>

#define DIM 128
#define NUM_OUT 100000
#define N_SRC 200000
#define NT_TILES (N_SRC / 16)
#define OFFS_BYTES (((4 * (NUM_OUT + 1)) + 511) / 512 * 512)
#define WT_BYTES (DIM * DIM * 2)

typedef float v2f __attribute__((ext_vector_type(2)));
typedef float v4f __attribute__((ext_vector_type(4)));
typedef float f32x4 __attribute__((ext_vector_type(4)));
typedef _Float16 f16x2 __attribute__((ext_vector_type(2)));
typedef _Float16 f16x8 __attribute__((ext_vector_type(8)));

__device__ __forceinline__ float fast_tanh(float x) {
  const float xc = fminf(fmaxf(x, -15.f), 15.f);
  const float t = __expf(2.f * xc);
  return __fdividef(t - 1.f, t + 1.f);
}

__device__ __forceinline__ f16x8 cvt8(v4f a, v4f b) {
  f16x8 h;
  h[0] = (_Float16)a.x; h[1] = (_Float16)a.y;
  h[2] = (_Float16)a.z; h[3] = (_Float16)a.w;
  h[4] = (_Float16)b.x; h[5] = (_Float16)b.y;
  h[6] = (_Float16)b.z; h[7] = (_Float16)b.w;
  return h;
}

// Kernel 0 (merged): blocks [0,64) build Wt fp16; blocks [64,...) build offs.
__global__ __launch_bounds__(256) void prep(
    const int* __restrict__ seg, int* __restrict__ offs,
    const float* __restrict__ W, _Float16* __restrict__ Wt,
    int n_edges, int n_out) {
  if (blockIdx.x < 64) {
    const int i = blockIdx.x * 256 + threadIdx.x;  // < 16384
    const int k = i >> 7, n = i & 127;
    Wt[n * DIM + k] = (_Float16)W[i];
    return;
  }
  const int e = (blockIdx.x - 64) * 256 + threadIdx.x;
  if (e >= n_edges) return;
  const int se = seg[e];
  const int sp = (e == 0) ? -1 : seg[e - 1];
  for (int s = sp + 1; s <= se; ++s) offs[s] = e;
  if (e == n_edges - 1) {
    for (int s = se + 1; s <= n_out; ++s) offs[s] = n_edges;
  }
}

#define LOAD8(Qp, tidx) do {                                      \
  const float* xp_ = x + (size_t)((tidx) * 16 + ar) * DIM + kblk; \
  Qp##0 = *(const v4f*)(xp_ + 0);                                 \
  Qp##1 = *(const v4f*)(xp_ + 4);                                 \
  Qp##2 = *(const v4f*)(xp_ + 32);                                \
  Qp##3 = *(const v4f*)(xp_ + 36);                                \
  Qp##4 = *(const v4f*)(xp_ + 64);                                \
  Qp##5 = *(const v4f*)(xp_ + 68);                                \
  Qp##6 = *(const v4f*)(xp_ + 96);                                \
  Qp##7 = *(const v4f*)(xp_ + 100);                               \
} while (0)

#define STEP(Qc, tcur, pf_ok, tpf, Qp) do {                                        \
  f16x8 af_[4];                                                                    \
  af_[0] = cvt8(Qc##0, Qc##1); af_[1] = cvt8(Qc##2, Qc##3);                        \
  af_[2] = cvt8(Qc##4, Qc##5); af_[3] = cvt8(Qc##6, Qc##7);                        \
  if (pf_ok) { LOAD8(Qp, tpf); }                                                   \
  __builtin_amdgcn_sched_barrier(0);                                               \
  f32x4 acc_[8];                                                                   \
  _Pragma("unroll") for (int nt = 0; nt < 8; ++nt)                                 \
    acc_[nt] = (f32x4){0.f, 0.f, 0.f, 0.f};                                        \
  _Pragma("unroll") for (int kb = 0; kb < 4; ++kb) {                               \
    f16x8 bf_[4];                                                                  \
    _Pragma("unroll") for (int nt = 0; nt < 4; ++nt)                               \
      bf_[nt] = *(const f16x8*)(Wt + (size_t)(nt * 16 + cc) * DIM + kb * 32 + kblk); \
    _Pragma("unroll") for (int nt = 0; nt < 4; ++nt)                               \
      acc_[nt] = __builtin_amdgcn_mfma_f32_16x16x32_f16(af_[kb], bf_[nt], acc_[nt], 0, 0, 0); \
    _Pragma("unroll") for (int nt = 4; nt < 8; ++nt)                               \
      bf_[nt - 4] = *(const f16x8*)(Wt + (size_t)(nt * 16 + cc) * DIM + kb * 32 + kblk); \
    _Pragma("unroll") for (int nt = 4; nt < 8; ++nt)                               \
      acc_[nt] = __builtin_amdgcn_mfma_f32_16x16x32_f16(af_[kb], bf_[nt - 4], acc_[nt], 0, 0, 0); \
  }                                                                                \
  const int zr0_ = (tcur) * 16 + cr0;                                              \
  _Pragma("unroll") for (int nt = 0; nt < 8; ++nt) {                               \
    const int zc_ = nt * 16 + cc;                                                  \
    _Pragma("unroll") for (int r = 0; r < 4; ++r)                                  \
      z[(size_t)(zr0_ + r) * DIM + zc_] = (_Float16)acc_[nt][r];                   \
  }                                                                                \
} while (0)

// Kernel 1: z = (fp16)(values @ W), f32 accum. PERSISTENT, DEPTH-2 PIPELINE:
// 2048 waves (1 block/CU) x ~6 tiles each; two register sets qA/qB, loads
// issued 2 tiles (~2 STEPs of MFMA+stores) ahead of use. Zero LDS.
// Fragment layout (R12-validated): A row=l&15, k at (l>>4)*8; B col=l&15;
// C/D col=l&15, row=(l>>4)*4+r.
__global__ __launch_bounds__(512, 2) void transform_mfma(
    const float* __restrict__ x,
    const _Float16* __restrict__ Wt,
    _Float16* __restrict__ z) {
  const int l = threadIdx.x & 63;
  const int wave_id = (blockIdx.x * 512 + threadIdx.x) >> 6;
  const int NW = (gridDim.x * 512) >> 6;

  const int ar = l & 15;          // A row within tile
  const int kblk = (l >> 4) * 8;  // k sub-block
  const int cc = l & 15;          // C col within 16-tile
  const int cr0 = (l >> 4) * 4;   // C row base within tile

  v4f qA0, qA1, qA2, qA3, qA4, qA5, qA6, qA7;
  v4f qB0, qB1, qB2, qB3, qB4, qB5, qB6, qB7;

  int t = wave_id;
  LOAD8(qA, t);
  if (t + NW < NT_TILES) LOAD8(qB, t + NW);

  while (t < NT_TILES) {
    STEP(qA, t, (t + 2 * NW) < NT_TILES, t + 2 * NW, qA);
    const int tb = t + NW;
    if (tb < NT_TILES) {
      STEP(qB, tb, (tb + 2 * NW) < NT_TILES, tb + 2 * NW, qB);
    }
    t += 2 * NW;
  }
}

// Kernel 2: pure gather+segsum+tanh over fp16 z rows (256 B each).
// Bytes-wall limited (~6.2 TB/s delivered incl L3 hits); proven, do not touch.
__global__ __launch_bounds__(128) void seg_gather_tanh(
    const _Float16* __restrict__ zh,
    const int* __restrict__ gidx,
    const int* __restrict__ offs,
    float* __restrict__ out,
    int n_edges) {
  const int s = blockIdx.x * 2 + (threadIdx.x >> 6);
  const int t = threadIdx.x & 63;

  const int e0 = __builtin_amdgcn_readfirstlane(offs[s]);
  const int e1 = __builtin_amdgcn_readfirstlane(offs[s + 1]);
  const int len = e1 - e0;

  const f16x2* __restrict__ z2 = (const f16x2*)zh;
  float accx = 0.f, accy = 0.f;

  for (int base = 0; base < len; base += 64) {
    const int my = gidx[min(e0 + base + t, n_edges - 1)];
    const int n = min(64, len - base);
    int k = 0;
    for (; k + 8 <= n; k += 8) {
      int r0 = __builtin_amdgcn_readlane(my, k + 0);
      int r1 = __builtin_amdgcn_readlane(my, k + 1);
      int r2 = __builtin_amdgcn_readlane(my, k + 2);
      int r3 = __builtin_amdgcn_readlane(my, k + 3);
      int r4 = __builtin_amdgcn_readlane(my, k + 4);
      int r5 = __builtin_amdgcn_readlane(my, k + 5);
      int r6 = __builtin_amdgcn_readlane(my, k + 6);
      int r7 = __builtin_amdgcn_readlane(my, k + 7);
      const f16x2 a0 = z2[(size_t)r0 * 64 + t];
      const f16x2 a1 = z2[(size_t)r1 * 64 + t];
      const f16x2 a2 = z2[(size_t)r2 * 64 + t];
      const f16x2 a3 = z2[(size_t)r3 * 64 + t];
      const f16x2 a4 = z2[(size_t)r4 * 64 + t];
      const f16x2 a5 = z2[(size_t)r5 * 64 + t];
      const f16x2 a6 = z2[(size_t)r6 * 64 + t];
      const f16x2 a7 = z2[(size_t)r7 * 64 + t];
      accx += (float)a0.x + (float)a1.x + (float)a2.x + (float)a3.x +
              (float)a4.x + (float)a5.x + (float)a6.x + (float)a7.x;
      accy += (float)a0.y + (float)a1.y + (float)a2.y + (float)a3.y +
              (float)a4.y + (float)a5.y + (float)a6.y + (float)a7.y;
    }
    if (k < n) {
      const int nm1 = n - 1;
#pragma unroll
      for (int j = 0; j < 7; j += 4) {
        if (k + j < n) {
          int q0 = __builtin_amdgcn_readlane(my, min(k + j + 0, nm1));
          int q1 = __builtin_amdgcn_readlane(my, min(k + j + 1, nm1));
          int q2 = __builtin_amdgcn_readlane(my, min(k + j + 2, nm1));
          int q3 = __builtin_amdgcn_readlane(my, min(k + j + 3, nm1));
          const float m1 = (k + j + 1 < n) ? 1.f : 0.f;
          const float m2 = (k + j + 2 < n) ? 1.f : 0.f;
          const float m3 = (k + j + 3 < n) ? 1.f : 0.f;
          const f16x2 b0 = z2[(size_t)q0 * 64 + t];
          const f16x2 b1 = z2[(size_t)q1 * 64 + t];
          const f16x2 b2 = z2[(size_t)q2 * 64 + t];
          const f16x2 b3 = z2[(size_t)q3 * 64 + t];
          accx += (float)b0.x + m1 * (float)b1.x + m2 * (float)b2.x + m3 * (float)b3.x;
          accy += (float)b0.y + m1 * (float)b1.y + m2 * (float)b2.y + m3 * (float)b3.y;
        }
      }
    }
  }

  v2f o;
  o.x = fast_tanh(accx);
  o.y = fast_tanh(accy);
  ((v2f*)out)[(size_t)s * 64 + t] = o;
}

extern "C" void kernel_launch(void* const* d_in, const int* in_sizes, int n_in,
                              void* d_out, int out_size, void* d_ws, size_t ws_size,
                              hipStream_t stream) {
  const float* values = (const float*)d_in[0];   // [N_SRC, 128] f32
  const float* W      = (const float*)d_in[1];   // [128, 128] f32
  const int*   gidx   = (const int*)d_in[2];     // [E] int
  const int*   seg    = (const int*)d_in[3];     // [E] int, sorted
  float* out = (float*)d_out;                    // [N_OUT, 128] f32

  int*      offs = (int*)d_ws;                                        // [N_OUT+1]
  _Float16* Wt   = (_Float16*)((char*)d_ws + OFFS_BYTES);             // [128,128] fp16
  _Float16* z    = (_Float16*)((char*)d_ws + OFFS_BYTES + WT_BYTES);  // [N_SRC,128] fp16

  const int n_edges = in_sizes[2];

  prep<<<64 + (n_edges + 255) / 256, 256, 0, stream>>>(seg, offs, W, Wt, n_edges, NUM_OUT);
  transform_mfma<<<256, 512, 0, stream>>>(values, Wt, z);
  seg_gather_tanh<<<NUM_OUT / 2, 128, 0, stream>>>(z, gidx, offs, out, n_edges);
}

// Round 18
// 109.559 us; speedup vs baseline: 1.3340x; 1.3340x over previous
//
#include <hip/hip_runtime.h>

#define DIM 128
#define NUM_OUT 100000
#define N_SRC 200000
#define NT_TILES (N_SRC / 16)
#define OFFS_BYTES (((4 * (NUM_OUT + 1)) + 511) / 512 * 512)
#define WT_BYTES (DIM * DIM * 2)

typedef float v2f __attribute__((ext_vector_type(2)));
typedef float v4f __attribute__((ext_vector_type(4)));
typedef float f32x4 __attribute__((ext_vector_type(4)));
typedef _Float16 f16x2 __attribute__((ext_vector_type(2)));
typedef _Float16 f16x8 __attribute__((ext_vector_type(8)));

__device__ __forceinline__ float fast_tanh(float x) {
  const float xc = fminf(fmaxf(x, -15.f), 15.f);
  const float t = __expf(2.f * xc);
  return __fdividef(t - 1.f, t + 1.f);
}

__device__ __forceinline__ f16x8 cvt8(v4f a, v4f b) {
  f16x8 h;
  h[0] = (_Float16)a.x; h[1] = (_Float16)a.y;
  h[2] = (_Float16)a.z; h[3] = (_Float16)a.w;
  h[4] = (_Float16)b.x; h[5] = (_Float16)b.y;
  h[6] = (_Float16)b.z; h[7] = (_Float16)b.w;
  return h;
}

// Kernel 0 (merged): blocks [0,64) build Wt fp16; blocks [64,...) build offs.
__global__ __launch_bounds__(256) void prep(
    const int* __restrict__ seg, int* __restrict__ offs,
    const float* __restrict__ W, _Float16* __restrict__ Wt,
    int n_edges, int n_out) {
  if (blockIdx.x < 64) {
    const int i = blockIdx.x * 256 + threadIdx.x;  // < 16384
    const int k = i >> 7, n = i & 127;
    Wt[n * DIM + k] = (_Float16)W[i];
    return;
  }
  const int e = (blockIdx.x - 64) * 256 + threadIdx.x;
  if (e >= n_edges) return;
  const int se = seg[e];
  const int sp = (e == 0) ? -1 : seg[e - 1];
  for (int s = sp + 1; s <= se; ++s) offs[s] = e;
  if (e == n_edges - 1) {
    for (int s = se + 1; s <= n_out; ++s) offs[s] = n_edges;
  }
}

// Kernel 1: z = (fp16)(values @ W), f32 accum. PERSISTENT-PIPELINED (R16-
// proven, ~42 us): 4096 waves (512 blk x 512 thr, 2 blk/CU, 4 waves/SIMD)
// grid-stride over 12500 16-row tiles (~3 tiles/wave). Per iteration: cvt
// current tile, ISSUE next tile's 8 x-loads (hidden under 32 MFMAs + L1 Wt
// loads), pinned by sched_barrier. Zero LDS, VGPR ~60.
// NOTE R17 lesson: 256 blk + depth-2 prefetch REGRESSED 2.2x (TLP collapse,
// VGPR 128) — wave-count TLP dominates in-wave pipeline depth here.
// Fragment layout (R12-validated): A row=l&15, k at (l>>4)*8; B col=l&15;
// C/D col=l&15, row=(l>>4)*4+r.
__global__ __launch_bounds__(512) void transform_mfma(
    const float* __restrict__ x,
    const _Float16* __restrict__ Wt,
    _Float16* __restrict__ z) {
  const int l = threadIdx.x & 63;
  const int wave_id = (blockIdx.x * 512 + threadIdx.x) >> 6;
  const int num_waves = (gridDim.x * 512) >> 6;

  const int ar = l & 15;          // A row within tile
  const int kblk = (l >> 4) * 8;  // k sub-block
  const int cc = l & 15;          // C col within 16-tile
  const int cr0 = (l >> 4) * 4;   // C row base within tile

  int tile = wave_id;

  // prologue: loads for first tile
  const float* xr = x + (size_t)(tile * 16 + ar) * DIM + kblk;
  v4f q0 = *(const v4f*)(xr + 0);
  v4f q1 = *(const v4f*)(xr + 4);
  v4f q2 = *(const v4f*)(xr + 32);
  v4f q3 = *(const v4f*)(xr + 36);
  v4f q4 = *(const v4f*)(xr + 64);
  v4f q5 = *(const v4f*)(xr + 68);
  v4f q6 = *(const v4f*)(xr + 96);
  v4f q7 = *(const v4f*)(xr + 100);

  while (tile < NT_TILES) {
    const int next = tile + num_waves;

    f16x8 af[4];
    af[0] = cvt8(q0, q1);
    af[1] = cvt8(q2, q3);
    af[2] = cvt8(q4, q5);
    af[3] = cvt8(q6, q7);

    // issue next tile's loads now; they complete under the MFMA section
    if (next < NT_TILES) {
      const float* xn = x + (size_t)(next * 16 + ar) * DIM + kblk;
      q0 = *(const v4f*)(xn + 0);
      q1 = *(const v4f*)(xn + 4);
      q2 = *(const v4f*)(xn + 32);
      q3 = *(const v4f*)(xn + 36);
      q4 = *(const v4f*)(xn + 64);
      q5 = *(const v4f*)(xn + 68);
      q6 = *(const v4f*)(xn + 96);
      q7 = *(const v4f*)(xn + 100);
    }
    __builtin_amdgcn_sched_barrier(0);

    f32x4 acc[8];
#pragma unroll
    for (int nt = 0; nt < 8; ++nt) acc[nt] = (f32x4){0.f, 0.f, 0.f, 0.f};

#pragma unroll
    for (int kb = 0; kb < 4; ++kb) {
      f16x8 bf[8];
#pragma unroll
      for (int nt = 0; nt < 8; ++nt)
        bf[nt] = *(const f16x8*)(Wt + (size_t)(nt * 16 + cc) * DIM + kb * 32 + kblk);
#pragma unroll
      for (int nt = 0; nt < 8; ++nt)
        acc[nt] = __builtin_amdgcn_mfma_f32_16x16x32_f16(af[kb], bf[nt], acc[nt], 0, 0, 0);
    }

    const int zr0 = tile * 16 + cr0;
#pragma unroll
    for (int nt = 0; nt < 8; ++nt) {
      const int zc = nt * 16 + cc;
#pragma unroll
      for (int r = 0; r < 4; ++r)
        z[(size_t)(zr0 + r) * DIM + zc] = (_Float16)acc[nt][r];
    }

    tile = next;
  }
}

// Kernel 2: pure gather+segsum+tanh over fp16 z rows (256 B each).
// Bytes-wall limited (~6.2 TB/s delivered incl L3 hits); proven, do not touch.
__global__ __launch_bounds__(128) void seg_gather_tanh(
    const _Float16* __restrict__ zh,
    const int* __restrict__ gidx,
    const int* __restrict__ offs,
    float* __restrict__ out,
    int n_edges) {
  const int s = blockIdx.x * 2 + (threadIdx.x >> 6);
  const int t = threadIdx.x & 63;

  const int e0 = __builtin_amdgcn_readfirstlane(offs[s]);
  const int e1 = __builtin_amdgcn_readfirstlane(offs[s + 1]);
  const int len = e1 - e0;

  const f16x2* __restrict__ z2 = (const f16x2*)zh;
  float accx = 0.f, accy = 0.f;

  for (int base = 0; base < len; base += 64) {
    const int my = gidx[min(e0 + base + t, n_edges - 1)];
    const int n = min(64, len - base);
    int k = 0;
    for (; k + 8 <= n; k += 8) {
      int r0 = __builtin_amdgcn_readlane(my, k + 0);
      int r1 = __builtin_amdgcn_readlane(my, k + 1);
      int r2 = __builtin_amdgcn_readlane(my, k + 2);
      int r3 = __builtin_amdgcn_readlane(my, k + 3);
      int r4 = __builtin_amdgcn_readlane(my, k + 4);
      int r5 = __builtin_amdgcn_readlane(my, k + 5);
      int r6 = __builtin_amdgcn_readlane(my, k + 6);
      int r7 = __builtin_amdgcn_readlane(my, k + 7);
      const f16x2 a0 = z2[(size_t)r0 * 64 + t];
      const f16x2 a1 = z2[(size_t)r1 * 64 + t];
      const f16x2 a2 = z2[(size_t)r2 * 64 + t];
      const f16x2 a3 = z2[(size_t)r3 * 64 + t];
      const f16x2 a4 = z2[(size_t)r4 * 64 + t];
      const f16x2 a5 = z2[(size_t)r5 * 64 + t];
      const f16x2 a6 = z2[(size_t)r6 * 64 + t];
      const f16x2 a7 = z2[(size_t)r7 * 64 + t];
      accx += (float)a0.x + (float)a1.x + (float)a2.x + (float)a3.x +
              (float)a4.x + (float)a5.x + (float)a6.x + (float)a7.x;
      accy += (float)a0.y + (float)a1.y + (float)a2.y + (float)a3.y +
              (float)a4.y + (float)a5.y + (float)a6.y + (float)a7.y;
    }
    if (k < n) {
      const int nm1 = n - 1;
#pragma unroll
      for (int j = 0; j < 7; j += 4) {
        if (k + j < n) {
          int q0 = __builtin_amdgcn_readlane(my, min(k + j + 0, nm1));
          int q1 = __builtin_amdgcn_readlane(my, min(k + j + 1, nm1));
          int q2 = __builtin_amdgcn_readlane(my, min(k + j + 2, nm1));
          int q3 = __builtin_amdgcn_readlane(my, min(k + j + 3, nm1));
          const float m1 = (k + j + 1 < n) ? 1.f : 0.f;
          const float m2 = (k + j + 2 < n) ? 1.f : 0.f;
          const float m3 = (k + j + 3 < n) ? 1.f : 0.f;
          const f16x2 b0 = z2[(size_t)q0 * 64 + t];
          const f16x2 b1 = z2[(size_t)q1 * 64 + t];
          const f16x2 b2 = z2[(size_t)q2 * 64 + t];
          const f16x2 b3 = z2[(size_t)q3 * 64 + t];
          accx += (float)b0.x + m1 * (float)b1.x + m2 * (float)b2.x + m3 * (float)b3.x;
          accy += (float)b0.y + m1 * (float)b1.y + m2 * (float)b2.y + m3 * (float)b3.y;
        }
      }
    }
  }

  v2f o;
  o.x = fast_tanh(accx);
  o.y = fast_tanh(accy);
  ((v2f*)out)[(size_t)s * 64 + t] = o;
}

extern "C" void kernel_launch(void* const* d_in, const int* in_sizes, int n_in,
                              void* d_out, int out_size, void* d_ws, size_t ws_size,
                              hipStream_t stream) {
  const float* values = (const float*)d_in[0];   // [N_SRC, 128] f32
  const float* W      = (const float*)d_in[1];   // [128, 128] f32
  const int*   gidx   = (const int*)d_in[2];     // [E] int
  const int*   seg    = (const int*)d_in[3];     // [E] int, sorted
  float* out = (float*)d_out;                    // [N_OUT, 128] f32

  int*      offs = (int*)d_ws;                                        // [N_OUT+1]
  _Float16* Wt   = (_Float16*)((char*)d_ws + OFFS_BYTES);             // [128,128] fp16
  _Float16* z    = (_Float16*)((char*)d_ws + OFFS_BYTES + WT_BYTES);  // [N_SRC,128] fp16

  const int n_edges = in_sizes[2];

  prep<<<64 + (n_edges + 255) / 256, 256, 0, stream>>>(seg, offs, W, Wt, n_edges, NUM_OUT);
  transform_mfma<<<512, 512, 0, stream>>>(values, Wt, z);
  seg_gather_tanh<<<NUM_OUT / 2, 128, 0, stream>>>(z, gidx, offs, out, n_edges);
}